// Round 1
// baseline (104.456 us; speedup 1.0000x reference)
//
#include <hip/hip_runtime.h>
#include <math.h>

#define B_SZ 2048
#define N_SZ 16384
#define D_SZ 64
#define P_SZ 5

#define BM 64      // rows per block
#define BN 128     // items per block
#define LDT 68     // padded LDS row stride (floats): 68 % 32 == 4 -> conflict-free frag reads
#define NCB (N_SZ / BN)   // 128 column blocks

// workspace layout in floats
#define WS_V2   0
#define WS_U2   (WS_V2 + N_SZ)
#define WS_POS  (WS_U2 + B_SZ)
#define WS_PM   (WS_POS + B_SZ)
#define WS_PS   (WS_PM + B_SZ * NCB)
// total = WS_PS + B_SZ*NCB floats ~= 2.2 MB

__global__ void norms_k(const float* __restrict__ u, const float* __restrict__ v,
                        float* __restrict__ ws) {
    int j = blockIdx.x * 256 + threadIdx.x;
    float* v2 = ws + WS_V2;
    float* u2 = ws + WS_U2;
    if (j < N_SZ) {
        const float4* p = (const float4*)(v + (size_t)j * D_SZ);
        float s = 0.f;
#pragma unroll
        for (int i = 0; i < D_SZ / 4; ++i) {
            float4 x = p[i];
            s += x.x * x.x + x.y * x.y + x.z * x.z + x.w * x.w;
        }
        v2[j] = s;
    }
    if (j < B_SZ) {
        const float4* p = (const float4*)(u + (size_t)j * D_SZ);
        float s = 0.f;
#pragma unroll
        for (int i = 0; i < D_SZ / 4; ++i) {
            float4 x = p[i];
            s += x.x * x.x + x.y * x.y + x.z * x.z + x.w * x.w;
        }
        u2[j] = s;
    }
}

__global__ __launch_bounds__(256) void dist_k(const float* __restrict__ uem,
                                              const float* __restrict__ vem,
                                              const float* __restrict__ target,
                                              const int* __restrict__ iidx,
                                              const int* __restrict__ pidx,
                                              float* __restrict__ ws) {
    __shared__ float lds[(BM + BN) * LDT];
    float* Ut = lds;              // [BM][LDT]
    float* Vt = lds + BM * LDT;   // [BN][LDT]

    const int t = threadIdx.x;
    const int brow = blockIdx.y * BM;
    const int bcol = blockIdx.x * BN;

    // ---- stage tiles (global contiguous float4 -> LDS padded rows) ----
    {
        const float4* src = (const float4*)(uem + (size_t)brow * D_SZ);
#pragma unroll
        for (int it = 0; it < (BM * D_SZ / 4) / 256; ++it) {
            int idx = it * 256 + t;           // float4 index
            float4 x = src[idx];
            int e = idx * 4;
            int row = e >> 6, d = e & 63;
            *(float4*)&Ut[row * LDT + d] = x;
        }
        const float4* sv = (const float4*)(vem + (size_t)bcol * D_SZ);
#pragma unroll
        for (int it = 0; it < (BN * D_SZ / 4) / 256; ++it) {
            int idx = it * 256 + t;
            float4 x = sv[idx];
            int e = idx * 4;
            int row = e >> 6, d = e & 63;
            *(float4*)&Vt[row * LDT + d] = x;
        }
    }
    __syncthreads();

    const int w = t >> 6;        // wave 0..3 -> items [w*32, w*32+32)
    const int l = t & 63;
    const int lr = l >> 3;       // 0..7 row group
    const int lc = l & 7;        // 0..7 item group

    float acc[8][4];
#pragma unroll
    for (int ri = 0; ri < 8; ++ri)
#pragma unroll
        for (int ci = 0; ci < 4; ++ci) acc[ri][ci] = 0.f;

    // ---- main dot-product loop, 4 k's per step via float4 frags ----
#pragma unroll 4
    for (int k4 = 0; k4 < D_SZ / 4; ++k4) {
        float4 a[8], b[4];
#pragma unroll
        for (int ri = 0; ri < 8; ++ri)
            a[ri] = *(const float4*)&Ut[(lr + 8 * ri) * LDT + 4 * k4];
#pragma unroll
        for (int ci = 0; ci < 4; ++ci)
            b[ci] = *(const float4*)&Vt[(w * 32 + lc + 8 * ci) * LDT + 4 * k4];
#pragma unroll
        for (int ri = 0; ri < 8; ++ri)
#pragma unroll
            for (int ci = 0; ci < 4; ++ci) {
                acc[ri][ci] += a[ri].x * b[ci].x;
                acc[ri][ci] += a[ri].y * b[ci].y;
                acc[ri][ci] += a[ri].z * b[ci].z;
                acc[ri][ci] += a[ri].w * b[ci].w;
            }
    }

    // ---- epilogue: d2, sign, mask, pos capture, online (m,s) ----
    const float* v2 = ws + WS_V2;
    const float* u2 = ws + WS_U2;
    float* pos = ws + WS_POS;
    float* pm = ws + WS_PM;
    float* ps = ws + WS_PS;

    float v2c[4];
    int idc[4];
#pragma unroll
    for (int ci = 0; ci < 4; ++ci) {
        int C = bcol + w * 32 + lc + 8 * ci;
        v2c[ci] = v2[C];
        idc[ci] = iidx[C];
    }

    float m[8], ssum[8];
#pragma unroll
    for (int ri = 0; ri < 8; ++ri) {
        int R = brow + lr + 8 * ri;
        float u2r = u2[R];
        float tg = target[R];
        float sg = (tg > 0.f) ? 1.f : ((tg < 0.f) ? -1.f : 0.f);
        int idr = iidx[R];
        int p0 = pidx[R * P_SZ + 0];
        int p1 = pidx[R * P_SZ + 1];
        int p2 = pidx[R * P_SZ + 2];
        int p3 = pidx[R * P_SZ + 3];
        int p4 = pidx[R * P_SZ + 4];
        float vals[4];
        float mm = -1e30f;
#pragma unroll
        for (int ci = 0; ci < 4; ++ci) {
            int C = bcol + w * 32 + lc + 8 * ci;
            float d2 = u2r + v2c[ci] - 2.f * acc[ri][ci];
            float loss = -0.5f * fmaxf(d2, 0.f) * sg;
            if (C == R) pos[R] = loss;   // diagonal (exactly one block/lane hits it)
            int ic = idc[ci];
            bool msk = (ic == idr) | (ic == p0) | (ic == p1) | (ic == p2) | (ic == p3) | (ic == p4);
            float val = msk ? -1e30f : loss;
            vals[ci] = val;
            mm = fmaxf(mm, val);
        }
        float se = 0.f;
#pragma unroll
        for (int ci = 0; ci < 4; ++ci) se += __expf(vals[ci] - mm);
        m[ri] = mm;
        ssum[ri] = se;
    }

    // cross-lane (m,s) merge over the 8 item-lanes (xor 1,2,4)
#pragma unroll
    for (int ri = 0; ri < 8; ++ri) {
        float mm = m[ri], se = ssum[ri];
#pragma unroll
        for (int msk_ = 1; msk_ < 8; msk_ <<= 1) {
            float om = __shfl_xor(mm, msk_);
            float os = __shfl_xor(se, msk_);
            float M2 = fmaxf(mm, om);
            se = se * __expf(mm - M2) + os * __expf(om - M2);
            mm = M2;
        }
        m[ri] = mm;
        ssum[ri] = se;
    }

    // combine the 4 waves via LDS (overlay on tile memory after sync)
    __syncthreads();
    float* smm = lds;          // [4][64]
    float* sms = lds + 256;    // [4][64]
    if (lc == 0) {
#pragma unroll
        for (int ri = 0; ri < 8; ++ri) {
            int r = lr + 8 * ri;
            smm[w * 64 + r] = m[ri];
            sms[w * 64 + r] = ssum[ri];
        }
    }
    __syncthreads();
    if (t < 64) {
        float M = smm[t], S = sms[t];
#pragma unroll
        for (int ww = 1; ww < 4; ++ww) {
            float om = smm[ww * 64 + t], os = sms[ww * 64 + t];
            float M2 = fmaxf(M, om);
            S = S * __expf(M - M2) + os * __expf(om - M2);
            M = M2;
        }
        int R = brow + t;
        pm[(size_t)R * NCB + blockIdx.x] = M;
        ps[(size_t)R * NCB + blockIdx.x] = S;
    }
}

__global__ void finish_k(const float* __restrict__ target, const float* __restrict__ ws,
                         float* __restrict__ out) {
    int r = blockIdx.x * 256 + threadIdx.x;   // 0..2047
    const float* pos = ws + WS_POS;
    const float* pm = ws + WS_PM;
    const float* ps = ws + WS_PS;

    float p = pos[r];
    float M = p, S = 1.f;   // exp(p - M) = 1
    for (int cb = 0; cb < NCB; ++cb) {
        float mm = pm[(size_t)r * NCB + cb];
        float ss = ps[(size_t)r * NCB + cb];
        float M2 = fmaxf(M, mm);
        S = S * __expf(M - M2) + ss * __expf(mm - M2);
        M = M2;
    }
    float ce = logf(S) + M - p;
    float contrib = ce * fabsf(target[r]);

    // block reduce (4 waves of 64)
#pragma unroll
    for (int o = 32; o > 0; o >>= 1) contrib += __shfl_down(contrib, o);
    __shared__ float sred[4];
    if ((threadIdx.x & 63) == 0) sred[threadIdx.x >> 6] = contrib;
    __syncthreads();
    if (threadIdx.x == 0) {
        atomicAdd(out, sred[0] + sred[1] + sred[2] + sred[3]);
    }
}

extern "C" void kernel_launch(void* const* d_in, const int* in_sizes, int n_in,
                              void* d_out, int out_size, void* d_ws, size_t ws_size,
                              hipStream_t stream) {
    const float* uem = (const float*)d_in[0];
    const float* vem = (const float*)d_in[1];
    const float* target = (const float*)d_in[2];
    const int* iidx = (const int*)d_in[3];
    const int* pidx = (const int*)d_in[4];
    float* ws = (float*)d_ws;
    float* out = (float*)d_out;

    hipMemsetAsync(out, 0, sizeof(float), stream);

    norms_k<<<dim3(N_SZ / 256), dim3(256), 0, stream>>>(uem, vem, ws);

    dim3 grid(N_SZ / BN, B_SZ / BM);   // (128, 32)
    dist_k<<<grid, dim3(256), 0, stream>>>(uem, vem, target, iidx, pidx, ws);

    finish_k<<<dim3(B_SZ / 256), dim3(256), 0, stream>>>(target, ws, out);
}

// Round 2
// 61.698 us; speedup vs baseline: 1.6930x; 1.6930x over previous
//
#include <hip/hip_runtime.h>
#include <math.h>

#define B_SZ 2048
#define N_SZ 16384
#define D_SZ 64
#define P_SZ 5

#define BM 128
#define BN 128
#define NCB (N_SZ / BN)   // 128 column blocks
#define LDT 72            // LDS row stride (bf16 elems); 144B rows -> 2-way (free) frag conflicts

typedef __bf16 bf16x8 __attribute__((ext_vector_type(8)));
typedef __bf16 bf16x4 __attribute__((ext_vector_type(4)));
typedef float f32x4 __attribute__((ext_vector_type(4)));

// workspace layout in floats (total 544768 floats = 2.18 MB, same as proven R1)
#define WS_V2   0
#define WS_U2   (WS_V2 + N_SZ)
#define WS_POS  (WS_U2 + B_SZ)
#define WS_PM   (WS_POS + B_SZ)
#define WS_PS   (WS_PM + B_SZ * NCB)

__global__ void norms_k(const float* __restrict__ u, const float* __restrict__ v,
                        float* __restrict__ ws) {
    int j = blockIdx.x * 256 + threadIdx.x;
    float* v2 = ws + WS_V2;
    float* u2 = ws + WS_U2;
    if (j < N_SZ) {
        const float4* p = (const float4*)(v + (size_t)j * D_SZ);
        float s = 0.f;
#pragma unroll
        for (int i = 0; i < D_SZ / 4; ++i) {
            float4 x = p[i];
            s += x.x * x.x + x.y * x.y + x.z * x.z + x.w * x.w;
        }
        v2[j] = s;
    }
    if (j < B_SZ) {
        const float4* p = (const float4*)(u + (size_t)j * D_SZ);
        float s = 0.f;
#pragma unroll
        for (int i = 0; i < D_SZ / 4; ++i) {
            float4 x = p[i];
            s += x.x * x.x + x.y * x.y + x.z * x.z + x.w * x.w;
        }
        u2[j] = s;
    }
}

__global__ __launch_bounds__(256, 3) void dist_k(const float* __restrict__ uem,
                                                 const float* __restrict__ vem,
                                                 const float* __restrict__ target,
                                                 const int* __restrict__ iidx,
                                                 const int* __restrict__ pidx,
                                                 float* __restrict__ ws) {
    __shared__ __bf16 Ut[BM * LDT];
    __shared__ __bf16 Vt[BN * LDT];
    __shared__ unsigned int rowdat[BM * 8];
    __shared__ float colv2[BN];
    __shared__ int colid[BN];
    __shared__ float smg[2 * BM];
    __shared__ float ssg[2 * BM];

    const int t = threadIdx.x;
    // XCD-bijective swizzle: xcd gets a 16-wide bx slab for all by -> V slab L2-resident
    const int orig = blockIdx.x;
    const int xcd = orig & 7;
    const int idx = orig >> 3;          // 0..255
    const int bx = xcd * 16 + (idx & 15);
    const int by = idx >> 4;            // 0..15
    const int brow = by * BM, bcol = bx * BN;

    const float* v2 = ws + WS_V2;
    const float* u2 = ws + WS_U2;
    float* pos = ws + WS_POS;
    float* pm = ws + WS_PM;
    float* ps = ws + WS_PS;

    // ---- stage U,V tiles: fp32 global -> bf16 LDS (RNE via cast) ----
    {
        const float4* su = (const float4*)(uem + (size_t)brow * D_SZ);
        const float4* sv = (const float4*)(vem + (size_t)bcol * D_SZ);
#pragma unroll
        for (int i = 0; i < (BM * D_SZ / 4) / 256; ++i) {   // 8 iters
            int f = i * 256 + t;                 // float4 index over [128][16]
            int row = f >> 4, d0 = (f & 15) * 4;
            float4 x = su[f];
            bf16x4 h = { (__bf16)x.x, (__bf16)x.y, (__bf16)x.z, (__bf16)x.w };
            *(bf16x4*)&Ut[row * LDT + d0] = h;
            float4 y = sv[f];
            bf16x4 g = { (__bf16)y.x, (__bf16)y.y, (__bf16)y.z, (__bf16)y.w };
            *(bf16x4*)&Vt[row * LDT + d0] = g;
        }
    }
    // ---- stage per-row and per-col epilogue data ----
    if (t < BM) {
        int R = brow + t;
        float tg = target[R];
        float sg = (tg > 0.f) ? 1.f : ((tg < 0.f) ? -1.f : 0.f);
        unsigned int* rd = &rowdat[t * 8];
        rd[0] = __float_as_uint(u2[R]);
        rd[1] = __float_as_uint(-0.5f * sg);
        rd[2] = (unsigned int)iidx[R];
        const int* pp = pidx + (size_t)R * P_SZ;
        rd[3] = (unsigned int)pp[0];
        rd[4] = (unsigned int)pp[1];
        rd[5] = (unsigned int)pp[2];
        rd[6] = (unsigned int)pp[3];
        rd[7] = (unsigned int)pp[4];
        colv2[t] = v2[bcol + t];
        colid[t] = iidx[bcol + t];
    }
    __syncthreads();

    const int w = t >> 6, l = t & 63;
    const int wr = w >> 1, wc = w & 1;   // wave tile: rows [wr*64,+64), cols [wc*64,+64)
    const int lr = l & 15, kg = l >> 4;

    // ---- MFMA phase: wave computes 64x64 via 4x4 fragments x 2 K-steps ----
    f32x4 acc[4][4];
#pragma unroll
    for (int mt = 0; mt < 4; ++mt)
#pragma unroll
        for (int nt = 0; nt < 4; ++nt)
            acc[mt][nt] = (f32x4){0.f, 0.f, 0.f, 0.f};

    bf16x8 af[4][2];
#pragma unroll
    for (int mt = 0; mt < 4; ++mt)
#pragma unroll
        for (int kk = 0; kk < 2; ++kk)
            af[mt][kk] = *(const bf16x8*)&Ut[(wr * 64 + mt * 16 + lr) * LDT + kk * 32 + kg * 8];

#pragma unroll
    for (int nt = 0; nt < 4; ++nt) {
        bf16x8 b0 = *(const bf16x8*)&Vt[(wc * 64 + nt * 16 + lr) * LDT + kg * 8];
        bf16x8 b1 = *(const bf16x8*)&Vt[(wc * 64 + nt * 16 + lr) * LDT + 32 + kg * 8];
#pragma unroll
        for (int mt = 0; mt < 4; ++mt) {
            acc[mt][nt] = __builtin_amdgcn_mfma_f32_16x16x32_bf16(af[mt][0], b0, acc[mt][nt], 0, 0, 0);
            acc[mt][nt] = __builtin_amdgcn_mfma_f32_16x16x32_bf16(af[mt][1], b1, acc[mt][nt], 0, 0, 0);
        }
    }

    // ---- epilogue: d2, sign, mask, diag capture, per-row (m,s) ----
    float v2c[4];
    int icv[4];
#pragma unroll
    for (int nt = 0; nt < 4; ++nt) {
        int c = wc * 64 + nt * 16 + lr;
        v2c[nt] = colv2[c];
        icv[nt] = colid[c];
    }
    const bool diag = (bx == by);

#pragma unroll
    for (int mt = 0; mt < 4; ++mt) {
#pragma unroll
        for (int reg = 0; reg < 4; ++reg) {
            const int rb = wr * 64 + mt * 16 + kg * 4 + reg;   // C row = (lane>>4)*4+reg (m89)
            const unsigned int* rd = &rowdat[rb * 8];
            const float u2r = __uint_as_float(rd[0]);
            const float msg = __uint_as_float(rd[1]);
            const int idr = (int)rd[2];
            const int p0 = (int)rd[3], p1 = (int)rd[4], p2 = (int)rd[5],
                      p3 = (int)rd[6], p4 = (int)rd[7];
            float vals[4];
            float mm = -3e38f;
#pragma unroll
            for (int nt = 0; nt < 4; ++nt) {
                float d2 = fmaf(-2.f, acc[mt][nt][reg], u2r + v2c[nt]);
                d2 = fmaxf(d2, 0.f);
                float loss = d2 * msg;
                if (diag) {                                    // only 16/2048 blocks
                    int C = bcol + wc * 64 + nt * 16 + lr;     // C col = lane&15 (m89)
                    int R = brow + rb;
                    if (C == R) pos[R] = loss;                 // unmasked diagonal
                }
                int ic = icv[nt];
                bool mk = (ic == idr) | (ic == p0) | (ic == p1) | (ic == p2) |
                          (ic == p3) | (ic == p4);
                float val = mk ? -3e38f : loss;
                vals[nt] = val;
                mm = fmaxf(mm, val);
            }
            float se = __expf(vals[0] - mm) + __expf(vals[1] - mm) +
                       __expf(vals[2] - mm) + __expf(vals[3] - mm);
            // merge (m,s) across the 16 col-lanes sharing this row
#pragma unroll
            for (int msk = 1; msk < 16; msk <<= 1) {
                float om = __shfl_xor(mm, msk);
                float os = __shfl_xor(se, msk);
                float M2 = fmaxf(mm, om);
                se = se * __expf(mm - M2) + os * __expf(om - M2);
                mm = M2;
            }
            if (lr == 0) {
                smg[wc * BM + rb] = mm;
                ssg[wc * BM + rb] = se;
            }
        }
    }
    __syncthreads();
    // merge the two col-half waves, write one partial per (row, n-block)
    if (t < BM) {
        float M = smg[t], S = ssg[t];
        float om = smg[BM + t], os = ssg[BM + t];
        float M2 = fmaxf(M, om);
        S = S * __expf(M - M2) + os * __expf(om - M2);
        pm[(size_t)(brow + t) * NCB + bx] = M2;
        ps[(size_t)(brow + t) * NCB + bx] = S;
    }
}

__global__ void finish_k(const float* __restrict__ target, const float* __restrict__ ws,
                         float* __restrict__ out) {
    int r = blockIdx.x * 256 + threadIdx.x;   // 0..2047
    const float* pos = ws + WS_POS;
    const float* pm = ws + WS_PM;
    const float* ps = ws + WS_PS;

    float p = pos[r];
    float M = p, S = 1.f;   // exp(p - M) = 1
    for (int cb = 0; cb < NCB; ++cb) {
        float mm = pm[(size_t)r * NCB + cb];
        float ss = ps[(size_t)r * NCB + cb];
        float M2 = fmaxf(M, mm);
        S = S * __expf(M - M2) + ss * __expf(mm - M2);
        M = M2;
    }
    float ce = logf(S) + M - p;
    float contrib = ce * fabsf(target[r]);

#pragma unroll
    for (int o = 32; o > 0; o >>= 1) contrib += __shfl_down(contrib, o);
    __shared__ float sred[4];
    if ((threadIdx.x & 63) == 0) sred[threadIdx.x >> 6] = contrib;
    __syncthreads();
    if (threadIdx.x == 0) {
        atomicAdd(out, sred[0] + sred[1] + sred[2] + sred[3]);
    }
}

extern "C" void kernel_launch(void* const* d_in, const int* in_sizes, int n_in,
                              void* d_out, int out_size, void* d_ws, size_t ws_size,
                              hipStream_t stream) {
    const float* uem = (const float*)d_in[0];
    const float* vem = (const float*)d_in[1];
    const float* target = (const float*)d_in[2];
    const int* iidx = (const int*)d_in[3];
    const int* pidx = (const int*)d_in[4];
    float* ws = (float*)d_ws;
    float* out = (float*)d_out;

    hipMemsetAsync(out, 0, sizeof(float), stream);

    norms_k<<<dim3(N_SZ / 256), dim3(256), 0, stream>>>(uem, vem, ws);

    dist_k<<<dim3((N_SZ / BN) * (B_SZ / BM)), dim3(256), 0, stream>>>(uem, vem, target, iidx, pidx, ws);

    finish_k<<<dim3(B_SZ / 256), dim3(256), 0, stream>>>(target, ws, out);
}

// Round 4
// 51.563 us; speedup vs baseline: 2.0258x; 1.1966x over previous
//
#include <hip/hip_runtime.h>
#include <math.h>

#define B_SZ 2048
#define N_SZ 16384
#define D_SZ 64
#define P_SZ 5

#define BM 128            // users per block
#define BN 128            // items per block
#define NCB (N_SZ / BN)   // 128 item blocks
#define LDT 72            // LDS row stride (bf16): 144B rows -> 2-way (free) frag conflicts

#define INVLN2 1.44269504088896340736f
#define LN2    0.69314718055994530942f
#define NEGHUGE (-3.0e38f)

typedef __bf16 bf16x8 __attribute__((ext_vector_type(8)));
typedef __bf16 bf16x4 __attribute__((ext_vector_type(4)));
typedef float f32x4 __attribute__((ext_vector_type(4)));

// workspace layout in floats (2.18 MB, same as proven R1/R2)
#define WS_V2   0
#define WS_U2   (WS_V2 + N_SZ)
#define WS_POS  (WS_U2 + B_SZ)
#define WS_PM   (WS_POS + B_SZ)
#define WS_PS   (WS_PM + B_SZ * NCB)

__global__ void norms_k(const float* __restrict__ u, const float* __restrict__ v,
                        float* __restrict__ ws) {
    int j = blockIdx.x * 256 + threadIdx.x;
    float* v2 = ws + WS_V2;
    float* u2 = ws + WS_U2;
    if (j < N_SZ) {
        const float4* p = (const float4*)(v + (size_t)j * D_SZ);
        float s = 0.f;
#pragma unroll
        for (int i = 0; i < D_SZ / 4; ++i) {
            float4 x = p[i];
            s += x.x * x.x + x.y * x.y + x.z * x.z + x.w * x.w;
        }
        v2[j] = s;
    }
    if (j < B_SZ) {
        const float4* p = (const float4*)(u + (size_t)j * D_SZ);
        float s = 0.f;
#pragma unroll
        for (int i = 0; i < D_SZ / 4; ++i) {
            float4 x = p[i];
            s += x.x * x.x + x.y * x.y + x.z * x.z + x.w * x.w;
        }
        u2[j] = s;
    }
}

__global__ __launch_bounds__(256, 3) void dist_k(const float* __restrict__ uem,
                                                 const float* __restrict__ vem,
                                                 const float* __restrict__ target,
                                                 const int* __restrict__ iidx,
                                                 const int* __restrict__ pidx,
                                                 float* __restrict__ ws) {
    __shared__ __bf16 Ut[BM * LDT];          // users
    __shared__ __bf16 Vt[BN * LDT];          // items
    __shared__ unsigned int rowdat[BM * 8];  // per-user: u2, msg2(log2), id, p0..p4
    __shared__ float colv2[BN];
    __shared__ int colid[BN];
    __shared__ unsigned int bloom[512];      // 16384-bit filter over (id & 16383)
    __shared__ unsigned int uflag[BM];       // per-user: any of its 6 ids maybe in tile
    __shared__ float smg[2 * BM];
    __shared__ float ssg[2 * BM];

    const int t = threadIdx.x;
    const int orig = blockIdx.x;
    const int xcd = orig & 7;
    const int idx = orig >> 3;
    const int bx = xcd * 16 + (idx & 15);    // item block 0..127
    const int by = idx >> 4;                 // user block 0..15
    const int brow = by * BM;                // user base
    const int bcol = bx * BN;                // item base

    const float* v2 = ws + WS_V2;
    const float* u2 = ws + WS_U2;
    float* pos = ws + WS_POS;
    float* pm = ws + WS_PM;
    float* ps = ws + WS_PS;

    // ---- phase A: stage tiles + per-user/per-item data, zero bloom ----
    bloom[t] = 0u;
    bloom[256 + t] = 0u;
    {
        const float4* su = (const float4*)(uem + (size_t)brow * D_SZ);
        const float4* sv = (const float4*)(vem + (size_t)bcol * D_SZ);
#pragma unroll
        for (int i = 0; i < 8; ++i) {
            int f = i * 256 + t;
            int row = f >> 4, d0 = (f & 15) * 4;
            float4 x = su[f];
            *(bf16x4*)&Ut[row * LDT + d0] =
                (bf16x4){(__bf16)x.x, (__bf16)x.y, (__bf16)x.z, (__bf16)x.w};
            float4 y = sv[f];
            *(bf16x4*)&Vt[row * LDT + d0] =
                (bf16x4){(__bf16)y.x, (__bf16)y.y, (__bf16)y.z, (__bf16)y.w};
        }
    }
    if (t < BM) {
        int U = brow + t;
        float tg = target[U];
        float sg = (tg > 0.f) ? 1.f : ((tg < 0.f) ? -1.f : 0.f);
        unsigned int* rd = &rowdat[t * 8];
        rd[0] = __float_as_uint(u2[U]);
        rd[1] = __float_as_uint(-0.5f * INVLN2 * sg);   // log2-domain sign factor
        rd[2] = (unsigned int)iidx[U];
        const int* pp = pidx + (size_t)U * P_SZ;
        rd[3] = (unsigned int)pp[0];
        rd[4] = (unsigned int)pp[1];
        rd[5] = (unsigned int)pp[2];
        rd[6] = (unsigned int)pp[3];
        rd[7] = (unsigned int)pp[4];
        colv2[t] = v2[bcol + t];
        colid[t] = iidx[bcol + t];
    }
    __syncthreads();                                   // bar1
    if (t < BN) {
        unsigned int h = (unsigned int)colid[t] & 16383u;
        atomicOr(&bloom[h >> 5], 1u << (h & 31));
    }
    __syncthreads();                                   // bar2
    if (t < BM) {
        const unsigned int* rd = &rowdat[t * 8];
        unsigned int fl = 0u;
#pragma unroll
        for (int j = 0; j < 6; ++j) {
            unsigned int h = rd[2 + j] & 16383u;
            fl |= (bloom[h >> 5] >> (h & 31)) & 1u;
        }
        uflag[t] = fl;
    }

    // ---- MFMA phase: operand-swapped (A=items, B=users) ----
    const int w = t >> 6, l = t & 63;
    const int wi = w >> 1;       // item half  [wi*64, +64)
    const int wu = w & 1;        // user half  [wu*64, +64)
    const int lr = l & 15, kg = l >> 4;

    f32x4 acc[4][4];             // [it][ut]
#pragma unroll
    for (int it = 0; it < 4; ++it)
#pragma unroll
        for (int ut = 0; ut < 4; ++ut)
            acc[it][ut] = (f32x4){0.f, 0.f, 0.f, 0.f};

    bf16x8 af[4][2];             // item fragments (A)
#pragma unroll
    for (int it = 0; it < 4; ++it)
#pragma unroll
        for (int kk = 0; kk < 2; ++kk)
            af[it][kk] = *(const bf16x8*)&Vt[(wi * 64 + it * 16 + lr) * LDT + kk * 32 + kg * 8];

#pragma unroll
    for (int ut = 0; ut < 4; ++ut) {
        bf16x8 b0 = *(const bf16x8*)&Ut[(wu * 64 + ut * 16 + lr) * LDT + kg * 8];
        bf16x8 b1 = *(const bf16x8*)&Ut[(wu * 64 + ut * 16 + lr) * LDT + 32 + kg * 8];
#pragma unroll
        for (int it = 0; it < 4; ++it) {
            acc[it][ut] = __builtin_amdgcn_mfma_f32_16x16x32_bf16(af[it][0], b0, acc[it][ut], 0, 0, 0);
            acc[it][ut] = __builtin_amdgcn_mfma_f32_16x16x32_bf16(af[it][1], b1, acc[it][ut], 0, 0, 0);
        }
    }
    __syncthreads();                                   // bar3: uflag/bloom ready

    // ---- epilogue: C layout col=lane&15=user, row=(lane>>4)*4+reg=item ----
    f32x4 v2q[4];
#pragma unroll
    for (int it = 0; it < 4; ++it)
        v2q[it] = *(const f32x4*)&colv2[wi * 64 + it * 16 + kg * 4];

    const bool diag = (bx == by);

#pragma unroll
    for (int ut = 0; ut < 4; ++ut) {
        const int ur = wu * 64 + ut * 16 + lr;         // user within block (= C col, lane&15)
        const float u2r = __uint_as_float(rowdat[ur * 8 + 0]);
        const float msg2 = __uint_as_float(rowdat[ur * 8 + 1]);
        const unsigned int fl = uflag[ur];

        float vals[16];
        // pass 1: raw log2-domain logits
#pragma unroll
        for (int it = 0; it < 4; ++it)
#pragma unroll
            for (int r = 0; r < 4; ++r) {
                float d2 = fmaf(-2.f, acc[it][ut][r], u2r + v2q[it][r]);
                vals[it * 4 + r] = fmaxf(d2, 0.f) * msg2;
            }
        // diagonal capture (pre-mask), only 16/2048 blocks
        if (diag) {
            const int U = brow + ur;
#pragma unroll
            for (int it = 0; it < 4; ++it)
#pragma unroll
                for (int r = 0; r < 4; ++r) {
                    int I = bcol + wi * 64 + it * 16 + kg * 4 + r;
                    if (I == U) pos[U] = vals[it * 4 + r];
                }
        }
        // rare slow path: exact id-mask
        if (fl) {
            const int idr = (int)rowdat[ur * 8 + 2];
            const int p0 = (int)rowdat[ur * 8 + 3], p1 = (int)rowdat[ur * 8 + 4],
                      p2 = (int)rowdat[ur * 8 + 5], p3 = (int)rowdat[ur * 8 + 6],
                      p4 = (int)rowdat[ur * 8 + 7];
#pragma unroll
            for (int it = 0; it < 4; ++it)
#pragma unroll
                for (int r = 0; r < 4; ++r) {
                    int ic = colid[wi * 64 + it * 16 + kg * 4 + r];
                    bool mk = (ic == idr) | (ic == p0) | (ic == p1) |
                              (ic == p2) | (ic == p3) | (ic == p4);
                    if (mk) vals[it * 4 + r] = NEGHUGE;
                }
        }
        // max-then-sum (items in-register, then lanes kg=0..3 via xor 16,32)
        float M = vals[0];
#pragma unroll
        for (int j = 1; j < 16; ++j) M = fmaxf(M, vals[j]);
        M = fmaxf(M, __shfl_xor(M, 16));
        M = fmaxf(M, __shfl_xor(M, 32));
        float S = 0.f;
#pragma unroll
        for (int j = 0; j < 16; ++j) S += exp2f(vals[j] - M);
        S += __shfl_xor(S, 16);
        S += __shfl_xor(S, 32);
        if (kg == 0) {
            smg[wi * BM + ur] = M;
            ssg[wi * BM + ur] = S;
        }
    }
    __syncthreads();                                   // bar4
    if (t < BM) {
        float M = smg[t], S = ssg[t];
        float om = smg[BM + t], os = ssg[BM + t];
        float M2 = fmaxf(M, om);
        S = S * exp2f(M - M2) + os * exp2f(om - M2);
        pm[(size_t)(brow + t) * NCB + bx] = M2;
        ps[(size_t)(brow + t) * NCB + bx] = S;
    }
}

__global__ __launch_bounds__(256) void finish_k(const float* __restrict__ target,
                                                const float* __restrict__ ws,
                                                float* __restrict__ out) {
    const int r = blockIdx.x * 4 + (threadIdx.x >> 6);  // one wave per row
    const int l = threadIdx.x & 63;
    const float* pos = ws + WS_POS;
    const float* pm = ws + WS_PM;
    const float* ps = ws + WS_PS;

    float M = pm[(size_t)r * NCB + l];
    float S = ps[(size_t)r * NCB + l];
    float m2 = pm[(size_t)r * NCB + 64 + l];
    float s2 = ps[(size_t)r * NCB + 64 + l];
    float Mx = fmaxf(M, m2);
    S = S * exp2f(M - Mx) + s2 * exp2f(m2 - Mx);
    M = Mx;
#pragma unroll
    for (int off = 1; off < 64; off <<= 1) {
        float om = __shfl_xor(M, off);
        float os = __shfl_xor(S, off);
        float M2 = fmaxf(M, om);
        S = S * exp2f(M - M2) + os * exp2f(om - M2);
        M = M2;
    }
    __shared__ float cred[4];
    if (l == 0) {
        float p = pos[r];
        float M2 = fmaxf(M, p);
        float St = S * exp2f(M - M2) + exp2f(p - M2);
        float ce = (__log2f(St) + M2 - p) * LN2;
        cred[threadIdx.x >> 6] = ce * fabsf(target[r]);
    }
    __syncthreads();
    if (threadIdx.x == 0)
        atomicAdd(out, cred[0] + cred[1] + cred[2] + cred[3]);
}

extern "C" void kernel_launch(void* const* d_in, const int* in_sizes, int n_in,
                              void* d_out, int out_size, void* d_ws, size_t ws_size,
                              hipStream_t stream) {
    const float* uem = (const float*)d_in[0];
    const float* vem = (const float*)d_in[1];
    const float* target = (const float*)d_in[2];
    const int* iidx = (const int*)d_in[3];
    const int* pidx = (const int*)d_in[4];
    float* ws = (float*)d_ws;
    float* out = (float*)d_out;

    hipMemsetAsync(out, 0, sizeof(float), stream);

    norms_k<<<dim3(N_SZ / 256), dim3(256), 0, stream>>>(uem, vem, ws);

    dist_k<<<dim3((N_SZ / BN) * (B_SZ / BM)), dim3(256), 0, stream>>>(uem, vem, target, iidx, pidx, ws);

    // one wave per row, 4 rows per block -> B_SZ/4 = 512 blocks (R3 bug: was 8)
    finish_k<<<dim3(B_SZ / 4), dim3(256), 0, stream>>>(target, ws, out);
}

// Round 5
// 42.698 us; speedup vs baseline: 2.4464x; 1.2076x over previous
//
#include <hip/hip_runtime.h>
#include <math.h>
#include <stdint.h>

#define B_SZ 2048
#define N_SZ 16384
#define D_SZ 64
#define P_SZ 5

#define BM 128
#define BN 128
#define NCB (N_SZ / BN)

#define INVLN2 1.44269504088896340736f
#define LN2    0.69314718055994530942f

typedef __bf16 bf16x8 __attribute__((ext_vector_type(8)));
typedef __bf16 bf16x4 __attribute__((ext_vector_type(4)));
typedef float f32x4 __attribute__((ext_vector_type(4)));

// ws layout (float units)
#define WS_S    0                          // [2048]  per-row sum of exp2(masked logits)
#define WS_POS  (WS_S + B_SZ)              // [2048]  diagonal logit (log2 domain)
#define WS_U2   (WS_POS + B_SZ)            // [2048]
#define WS_V2   (WS_U2 + B_SZ)             // [16384]
#define WS_UBF  (WS_V2 + N_SZ)             // bf16[2048*64], swizzled rows (byte ofs 90112, 16-aligned)
#define WS_VBF  (WS_UBF + B_SZ * D_SZ / 2) // bf16[16384*64], swizzled rows

// ---- prep: fp32 -> swizzled bf16 rows + norms. 16 lanes per row. ----
__global__ __launch_bounds__(256) void prep_k(const float* __restrict__ uem,
                                              const float* __restrict__ vem,
                                              float* __restrict__ ws) {
    const int rid = blockIdx.x * 16 + (threadIdx.x >> 4);   // 0..18431
    const int seg = threadIdx.x & 15;                       // float4 index in row
    const bool isU = rid < B_SZ;
    const int r = isU ? rid : rid - B_SZ;
    const float* src = (isU ? uem : vem) + (size_t)r * D_SZ;
    float4 x = ((const float4*)src)[seg];
    float nrm = x.x * x.x + x.y * x.y + x.z * x.z + x.w * x.w;
#pragma unroll
    for (int o = 1; o < 16; o <<= 1) nrm += __shfl_xor(nrm, o);
    // swizzled store: 16B group g at row-local group (g ^ (r&7))
    uint16_t* dst = (uint16_t*)(ws + (isU ? WS_UBF : WS_VBF)) + (size_t)r * D_SZ;
    int g = seg >> 1, p = seg & 1, r7 = r & 7;
    int off = (((g ^ r7) << 3) + (p << 2));                 // bf16-element offset
    bf16x4 h = {(__bf16)x.x, (__bf16)x.y, (__bf16)x.z, (__bf16)x.w};
    *(bf16x4*)(dst + off) = h;
    if (seg == 0) {
        if (isU) ws[WS_U2 + r] = nrm;
        else     ws[WS_V2 + r] = nrm;
    }
}

// swizzled byte offset of 16B-group g16 in row `row` of a [128][64]bf16 tile
#define SWZ(row, g16) (((row) << 7) + ((((g16) ^ ((row) & 7))) << 4))

__global__ __launch_bounds__(256, 4) void dist_k(const float* __restrict__ target,
                                                 const int* __restrict__ iidx,
                                                 const int* __restrict__ pidx,
                                                 float* __restrict__ ws) {
    __shared__ __bf16 Ut[BM * D_SZ];         // 16 KB, swizzled rows
    __shared__ __bf16 Vt[BN * D_SZ];         // 16 KB, swizzled rows
    __shared__ unsigned int rowdat[BM * 8];  // u2, msg2, id, p0..p4
    __shared__ float colv2[BN];
    __shared__ int colid[BN];
    __shared__ unsigned int bloom[512];      // 16384-bit filter over (id & 16383)
    __shared__ unsigned int uflag[BM];

    const int t = threadIdx.x;
    const int orig = blockIdx.x;
    const int bx = (orig & 7) * 16 + ((orig >> 3) & 15);    // item block 0..127 (XCD swizzle)
    const int by = orig >> 7;                               // user block 0..15
    const int brow = by * BM, bcol = bx * BN;

    float* wsS = ws + WS_S;
    float* pos = ws + WS_POS;
    const float* u2 = ws + WS_U2;
    const float* v2 = ws + WS_V2;
    const uint16_t* ubf = (const uint16_t*)(ws + WS_UBF);
    const uint16_t* vbf = (const uint16_t*)(ws + WS_VBF);

    const int w = t >> 6, l = t & 63;

    bloom[t] = 0u;
    bloom[256 + t] = 0u;

    // ---- async stage: linear copy of pre-swizzled bf16 tiles ----
    {
        const char* gu = (const char*)(ubf + (size_t)brow * D_SZ) + w * 4096 + l * 16;
        const char* gv = (const char*)(vbf + (size_t)bcol * D_SZ) + w * 4096 + l * 16;
        char* lu = (char*)Ut + w * 4096;
        char* lv = (char*)Vt + w * 4096;
#pragma unroll
        for (int i = 0; i < 4; ++i) {
            __builtin_amdgcn_global_load_lds(
                (const __attribute__((address_space(1))) void*)(gu + i * 1024),
                (__attribute__((address_space(3))) void*)(lu + i * 1024), 16, 0, 0);
            __builtin_amdgcn_global_load_lds(
                (const __attribute__((address_space(1))) void*)(gv + i * 1024),
                (__attribute__((address_space(3))) void*)(lv + i * 1024), 16, 0, 0);
        }
    }
    if (t < BM) {
        int U = brow + t;
        float tg = target[U];
        float sg = (tg > 0.f) ? 1.f : ((tg < 0.f) ? -1.f : 0.f);
        unsigned int* rd = &rowdat[t * 8];
        rd[0] = __float_as_uint(u2[U]);
        rd[1] = __float_as_uint(-0.5f * INVLN2 * sg);
        rd[2] = (unsigned int)iidx[U];
        const int* pp = pidx + (size_t)U * P_SZ;
        rd[3] = (unsigned int)pp[0];
        rd[4] = (unsigned int)pp[1];
        rd[5] = (unsigned int)pp[2];
        rd[6] = (unsigned int)pp[3];
        rd[7] = (unsigned int)pp[4];
        colv2[t] = v2[bcol + t];
        colid[t] = iidx[bcol + t];
    }
    __syncthreads();                         // bar1: tiles + scalars + bloom-zero done
    if (t < BN) {
        unsigned int h = (unsigned int)colid[t] & 16383u;
        atomicOr(&bloom[h >> 5], 1u << (h & 31));
    }
    __syncthreads();                         // bar2: bloom built

    const int wi = w >> 1;                   // item half
    const int wu = w & 1;                    // user half
    const int lr = l & 15, kg = l >> 4;

    if (t < BM) {                            // uflag overlaps MFMA phase
        const unsigned int* rd = &rowdat[t * 8];
        unsigned int fl = 0u;
#pragma unroll
        for (int j = 0; j < 6; ++j) {
            unsigned int h = rd[2 + j] & 16383u;
            fl |= (bloom[h >> 5] >> (h & 31)) & 1u;
        }
        uflag[t] = fl;
    }

    // ---- MFMA: A=items, B=users; kk-outer keeps live frags small ----
    const char* UtB = (const char*)Ut;
    const char* VtB = (const char*)Vt;
    f32x4 acc[4][4];                         // [it][ut]
#pragma unroll
    for (int it = 0; it < 4; ++it)
#pragma unroll
        for (int ut = 0; ut < 4; ++ut)
            acc[it][ut] = (f32x4){0.f, 0.f, 0.f, 0.f};

#pragma unroll
    for (int kk = 0; kk < 2; ++kk) {
        bf16x8 afk[4];
#pragma unroll
        for (int it = 0; it < 4; ++it)
            afk[it] = *(const bf16x8*)(VtB + SWZ(wi * 64 + it * 16 + lr, kk * 4 + kg));
#pragma unroll
        for (int ut = 0; ut < 4; ++ut) {
            bf16x8 bu = *(const bf16x8*)(UtB + SWZ(wu * 64 + ut * 16 + lr, kk * 4 + kg));
#pragma unroll
            for (int it = 0; it < 4; ++it)
                acc[it][ut] = __builtin_amdgcn_mfma_f32_16x16x32_bf16(afk[it], bu, acc[it][ut], 0, 0, 0);
        }
    }
    __syncthreads();                         // bar3: uflag ready

    // ---- epilogue: M=0 (logits <= 0), single exp pass, atomic row-sum ----
    f32x4 v2q[4];
#pragma unroll
    for (int it = 0; it < 4; ++it)
        v2q[it] = *(const f32x4*)&colv2[wi * 64 + it * 16 + kg * 4];

    const bool diag = (bx == by);

#pragma unroll
    for (int ut = 0; ut < 4; ++ut) {
        const int ur = wu * 64 + ut * 16 + lr;   // user = C col (lane&15)
        const float u2r = __uint_as_float(rowdat[ur * 8 + 0]);
        const float msg2 = __uint_as_float(rowdat[ur * 8 + 1]);
        const unsigned int fl = uflag[ur];
        int idr, p0, p1, p2, p3, p4;
        if (fl) {
            idr = (int)rowdat[ur * 8 + 2];
            p0 = (int)rowdat[ur * 8 + 3];
            p1 = (int)rowdat[ur * 8 + 4];
            p2 = (int)rowdat[ur * 8 + 5];
            p3 = (int)rowdat[ur * 8 + 6];
            p4 = (int)rowdat[ur * 8 + 7];
        }
        float S = 0.f;
#pragma unroll
        for (int it = 0; it < 4; ++it) {
#pragma unroll
            for (int r = 0; r < 4; ++r) {
                float d2 = fmaf(-2.f, acc[it][ut][r], u2r + v2q[it][r]);
                float v = fmaxf(d2, 0.f) * msg2;        // log2-domain logit, <= 0
                float e = exp2f(v);
                if (fl) {
                    int ic = colid[wi * 64 + it * 16 + kg * 4 + r];
                    if ((ic == idr) | (ic == p0) | (ic == p1) |
                        (ic == p2) | (ic == p3) | (ic == p4)) e = 0.f;
                }
                if (diag) {
                    int I = bcol + wi * 64 + it * 16 + kg * 4 + r;
                    if (I == brow + ur) pos[brow + ur] = v;   // unmasked diagonal
                }
                S += e;
            }
        }
        S += __shfl_xor(S, 16);
        S += __shfl_xor(S, 32);
        if (kg == 0) atomicAdd(&wsS[brow + ur], S);
    }
}

__global__ __launch_bounds__(256) void finish_k(const float* __restrict__ target,
                                                const float* __restrict__ ws,
                                                float* __restrict__ out) {
    const int r = blockIdx.x * 256 + threadIdx.x;   // 0..2047
    float p2 = ws[WS_POS + r];                      // log2 domain, <= 0
    float S = ws[WS_S + r];
    float ce = LN2 * (__log2f(exp2f(p2) + S) - p2);
    float c = ce * fabsf(target[r]);
#pragma unroll
    for (int o = 32; o > 0; o >>= 1) c += __shfl_down(c, o);
    __shared__ float sred[4];
    if ((threadIdx.x & 63) == 0) sred[threadIdx.x >> 6] = c;
    __syncthreads();
    if (threadIdx.x == 0)
        atomicAdd(out, sred[0] + sred[1] + sred[2] + sred[3]);
}

extern "C" void kernel_launch(void* const* d_in, const int* in_sizes, int n_in,
                              void* d_out, int out_size, void* d_ws, size_t ws_size,
                              hipStream_t stream) {
    const float* uem = (const float*)d_in[0];
    const float* vem = (const float*)d_in[1];
    const float* target = (const float*)d_in[2];
    const int* iidx = (const int*)d_in[3];
    const int* pidx = (const int*)d_in[4];
    float* ws = (float*)d_ws;
    float* out = (float*)d_out;

    hipMemsetAsync(out, 0, sizeof(float), stream);
    hipMemsetAsync(ws + WS_S, 0, B_SZ * sizeof(float), stream);   // per-row S accumulators

    prep_k<<<dim3((B_SZ + N_SZ) / 16), dim3(256), 0, stream>>>(uem, vem, ws);

    dist_k<<<dim3(NCB * (B_SZ / BM)), dim3(256), 0, stream>>>(target, iidx, pidx, ws);

    finish_k<<<dim3(B_SZ / 256), dim3(256), 0, stream>>>(target, ws, out);
}